// Round 18
// baseline (77.401 us; speedup 1.0000x reference)
//
#include <hip/hip_runtime.h>
#include <hip/hip_bf16.h>

// GraphAttentionV2 (B=8,SL=50,N=128,FIN=128,H=8,FH=32) — R18.
// Two-kernel split of R13's main: K1 = q,k + S (1 barrier, 26.6KB LDS);
// K2 = C2/LN/C1/FF/out (ZERO barriers, 9.2KB LDS, all B-operands in regs).
// Coupling scalar: S[bs,h,i] in ws (1.6MB). Same math as R13 (absmax-proven).

typedef __attribute__((ext_vector_type(8))) short bf16x8;
typedef __attribute__((ext_vector_type(4))) short bf16x4;
typedef __attribute__((ext_vector_type(4))) float f32x4;

#define MFMA16(a, b, c) __builtin_amdgcn_mfma_f32_16x16x32_bf16(a, b, c, 0, 0, 0)
#define EXP2F(x) __builtin_amdgcn_exp2f(x)

static __device__ __forceinline__ short f2b(float f) {
    __hip_bfloat16 b = __float2bfloat16(f);
    return *reinterpret_cast<short*>(&b);
}
static __device__ __forceinline__ bf16x8 ldb8(const short* p) {  // 2x ds_read_b64
    bf16x8 r;
    *(bf16x4*)&r = *(const bf16x4*)p;
    *((bf16x4*)&r + 1) = *(const bf16x4*)(p + 4);
    return r;
}
static __device__ __forceinline__ void ldg8(const float* p, float* d) {
    float4 x0 = *(const float4*)p, x1 = *(const float4*)(p + 4);
    d[0]=x0.x; d[1]=x0.y; d[2]=x0.z; d[3]=x0.w;
    d[4]=x1.x; d[5]=x1.y; d[6]=x1.z; d[7]=x1.w;
}

#define LOG2E 1.4426950408889634f
#define QSCALE (0.0055242717280199026f * 1.4426950408889634f)

// ---- workspace byte offsets ----
#define WS_MASK 0            // u32[400][128][4] = 819200
#define WS_WL   819200       // bf16 frag-order [8][4096] (pre-scaled by QSCALE)
#define WS_WR   884736       // pre-negated
#define WS_WAV  950272       // Wav = att_v @ Wv_h
#define WS_AS   1015808      // frag-order bf16[4096]
#define WS_W1   1024000
#define WS_W2   1026048
#define WS_VEC  1028096      // f32[517]
#define WS_S    1030720      // f32[400][8][128] = 1638400
#define WS_H0   2669120      // bf16[400][128][128] = 13107200 (big-ws only)
#define WS_NEED_BIG (WS_H0 + 13107200)

// ---- prep grid layout ----
#define PB_MASK   800
#define PB_W      816
#define PB_SMALL  817
#define PB_BIG    1217

// ---- K1 LDS (26624) ----
#define K1_WL  0             // 8192 frag Wl
#define K1_Q   8192          // short[128][36]=9216
#define K1_K   17408         // short[128][36]=9216
#define K1_TOTAL 26624
// ---- K2 LDS (9216) ----
#define K2_SC  0             // short[128][36]: sc -> f1 (own-wave stripes)
#define K2_TOTAL 9216

__global__ __launch_bounds__(256) void gat_prep(
    const float* __restrict__ adj,
    const float* __restrict__ Wl, const float* __restrict__ Wr, const float* __restrict__ Wv,
    const float* __restrict__ sa_w, const float* __restrict__ sa_b,
    const float* __restrict__ ln_w, const float* __restrict__ ln_b,
    const float* __restrict__ att_w, const float* __restrict__ att_b,
    const float* __restrict__ ff_w1, const float* __restrict__ ff_b1,
    const float* __restrict__ ff_w2, const float* __restrict__ ff_b2,
    const float* __restrict__ rezero, const float* __restrict__ h0,
    char* __restrict__ ws)
{
    const int t = threadIdx.x, bid = blockIdx.x;
    if (bid < PB_MASK) {
        const int tile = bid >> 1, half = bid & 1;
        const float* ab = adj + (size_t)tile * 16384;
        unsigned* mp = (unsigned*)(ws + WS_MASK) + tile * 512;
        const int w = t >> 6, l = t & 63;
        for (int rr = 0; rr < 16; ++rr) {
            int row = half * 64 + w * 16 + rr;
            float a0 = ab[row * 128 + l]      - ((row == l)      ? 1.f : 0.f);
            float a1 = ab[row * 128 + 64 + l] - ((row == 64 + l) ? 1.f : 0.f);
            unsigned long long m0 = __ballot(a0 >= 0.1f);   // bit=1: keep
            unsigned long long m1 = __ballot(a1 >= 0.1f);
            if (l == 0) {
                uint4 v; v.x = (unsigned)m0; v.y = (unsigned)(m0 >> 32);
                v.z = (unsigned)m1; v.w = (unsigned)(m1 >> 32);
                *(uint4*)(mp + row * 4) = v;
            }
        }
    } else if (bid < PB_W) {
        const int idx = bid - PB_MASK;
        const int h = idx >> 1, half = idx & 1;
        short* wl  = (short*)(ws + WS_WL)  + h * 4096;
        short* wr  = (short*)(ws + WS_WR)  + h * 4096;
        short* wav = (short*)(ws + WS_WAV) + h * 4096;
        const float* il = Wl + h * 4096;
        const float* ir = Wr + h * 4096;
        const float* iv = Wv + h * 4096;
        const int p = half * 256 + t;
        const int lo = p & 15, hi = (p >> 4) & 3, nt = (p >> 6) & 1, ks = p >> 7;
        const int src = (nt * 16 + lo) * 128 + ks * 32 + hi * 8;
        float x[8]; bf16x8 o;
        ldg8(il + src, x);
        #pragma unroll
        for (int e = 0; e < 8; ++e) o[e] = f2b(x[e] * QSCALE);
        *(bf16x8*)(wl + p * 8) = o;
        ldg8(ir + src, x);
        #pragma unroll
        for (int e = 0; e < 8; ++e) o[e] = f2b(-x[e]);
        *(bf16x8*)(wr + p * 8) = o;
        const int g = nt * 16 + lo, c0 = ks * 32 + hi * 8;
        float acc[8];
        #pragma unroll
        for (int e = 0; e < 8; ++e) acc[e] = 0.f;
        for (int f = 0; f < 32; ++f) {
            float a = att_w[g * 160 + 128 + f];
            float v8[8]; ldg8(iv + f * 128 + c0, v8);
            #pragma unroll
            for (int e = 0; e < 8; ++e) acc[e] = fmaf(a, v8[e], acc[e]);
        }
        #pragma unroll
        for (int e = 0; e < 8; ++e) o[e] = f2b(acc[e]);
        *(bf16x8*)(wav + p * 8) = o;
    } else if (bid == PB_W) {
        __shared__ float st[5];
        short* as_ = (short*)(ws + WS_AS);
        short* w1  = (short*)(ws + WS_W1);
        short* w2  = (short*)(ws + WS_W2);
        float* vec = (float*)(ws + WS_VEC);
        #pragma unroll
        for (int pp = 0; pp < 2; ++pp) {
            int p = t + pp * 256;
            int lo = p & 15, hi = (p >> 4) & 3, nt = (p >> 6) & 1, ks = p >> 7;
            float x[8]; bf16x8 o;
            ldg8(att_w + (nt * 16 + lo) * 160 + ks * 32 + hi * 8, x);
            #pragma unroll
            for (int e = 0; e < 8; ++e) o[e] = f2b(x[e]);
            *(bf16x8*)(as_ + p * 8) = o;
        }
        if (t < 128) {
            int p = t, lo = p & 15, hi = (p >> 4) & 3, nt = p >> 6;
            int r = nt * 16 + lo, c = hi * 8;
            float x[8]; bf16x8 o;
            ldg8(ff_w1 + r * 32 + c, x);
            #pragma unroll
            for (int e = 0; e < 8; ++e) o[e] = f2b(x[e]);
            *(bf16x8*)(w1 + p * 8) = o;
            ldg8(ff_w2 + r * 32 + c, x);
            #pragma unroll
            for (int e = 0; e < 8; ++e) o[e] = f2b(x[e]);
            *(bf16x8*)(w2 + p * 8) = o;
        }
        if (t < 64) {
            float w0 = sa_w[t], b0 = sa_b[t], w1f = sa_w[t + 64], b1f = sa_b[t + 64];
            float sw = w0 + w1f, sb = b0 + b1f;
            float sww = w0*w0 + w1f*w1f, swb = w0*b0 + w1f*b1f, sbb = b0*b0 + b1f*b1f;
            #pragma unroll
            for (int m = 1; m <= 32; m <<= 1) {
                sw += __shfl_xor(sw, m); sb += __shfl_xor(sb, m); sww += __shfl_xor(sww, m);
                swb += __shfl_xor(swb, m); sbb += __shfl_xor(sbb, m);
            }
            if (t == 0) {
                st[0] = sw / 128.f; st[1] = sb / 128.f; st[2] = sww / 128.f;
                st[3] = swb / 128.f; st[4] = sbb / 128.f;
                vec[512] = st[0]; vec[513] = st[1]; vec[514] = st[2];
                vec[515] = st[3]; vec[516] = st[4];
            }
        }
        __syncthreads();
        if (t < 128) {
            float lw = ln_w[t];
            vec[t]       = lw * (sa_w[t] - st[0]);   // A'
            vec[128 + t] = lw * (sa_b[t] - st[1]);   // B'
            vec[256 + t] = ln_b[t] * LOG2E;          // N
        } else if (t < 160) {
            int c = t - 128;
            vec[384 + c] = att_b[c];
            vec[416 + c] = ff_b1[c];
            vec[448 + c] = ff_b2[c];
            vec[480 + c] = rezero[c];
        }
    } else {
        const int bh = bid - PB_SMALL;
        const float* hp = h0 + (size_t)bh * 16384;
        short* op = (short*)(ws + WS_H0) + (size_t)bh * 16384;
        #pragma unroll
        for (int k = 0; k < 8; ++k) {
            int idx8 = t + k * 256;
            float x[8]; bf16x8 o;
            ldg8(hp + idx8 * 8, x);
            #pragma unroll
            for (int e = 0; e < 8; ++e) o[e] = f2b(x[e]);
            *(bf16x8*)(op + idx8 * 8) = o;
        }
    }
}

// ================= K1: q,k -> S =================
template<int PREH0>
__global__ __launch_bounds__(256, 2) void gat_k1(
    const float* __restrict__ h0, char* __restrict__ ws)
{
    const int t = threadIdx.x;
    const int bid  = blockIdx.x;
    const int slot = bid >> 3;
    const int bs   = (bid & 7) * 50 + (slot >> 3);
    const int h    = slot & 7;
    const int w = t >> 6, l = t & 63, lo = l & 15, hi = l >> 4;

    extern __shared__ char sm[];
    short* sWl = (short*)(sm + K1_WL);
    short* sq  = (short*)(sm + K1_Q);
    short* sk  = (short*)(sm + K1_K);
    const f32x4 Z4 = {0.f, 0.f, 0.f, 0.f};

    // Wr B-frags -> regs
    bf16x8 wrf[8];
    {
        const short* gWr = (const short*)(ws + WS_WR) + h * 4096;
        #pragma unroll
        for (int i = 0; i < 8; ++i)
            wrf[i] = *(const bf16x8*)(gWr + (i * 64 + l) * 8);
    }
    // stage Wl
    {
        const short* gWl = (const short*)(ws + WS_WL) + h * 4096;
        #pragma unroll
        for (int kk = 0; kk < 2; ++kk) {
            int p = t + kk * 256;
            *(bf16x8*)(sWl + p * 8) = *(const bf16x8*)(gWl + p * 8);
        }
    }
    __syncthreads();   // B0

    // ph1: q = h0@(QSCALE*Wl)^T, k = h0@(-Wr)^T
    #pragma unroll
    for (int mt = 0; mt < 2; ++mt) {
        bf16x8 af[4];
        if constexpr (PREH0) {
            const short* h0w = (const short*)(ws + WS_H0) + (size_t)bs * 16384;
            #pragma unroll
            for (int ks = 0; ks < 4; ++ks)
                af[ks] = *(const bf16x8*)(h0w + (w*32 + mt*16 + lo) * 128 + ks*32 + hi*8);
        } else {
            const float* rp = h0 + (size_t)bs * 16384 + (w*32 + mt*16 + lo) * 128;
            #pragma unroll
            for (int ks = 0; ks < 4; ++ks) {
                float x[8]; ldg8(rp + ks*32 + hi*8, x);
                #pragma unroll
                for (int r = 0; r < 8; ++r) af[ks][r] = f2b(x[r]);
            }
        }
        f32x4 cq[2], ck[2];
        cq[0]=Z4; cq[1]=Z4; ck[0]=Z4; ck[1]=Z4;
        #pragma unroll
        for (int ks = 0; ks < 4; ++ks)
            #pragma unroll
            for (int nt = 0; nt < 2; ++nt) {
                bf16x8 bq = *(const bf16x8*)(sWl + ((ks*2 + nt)*64 + l) * 8);
                cq[nt] = MFMA16(af[ks], bq, cq[nt]);
                ck[nt] = MFMA16(af[ks], wrf[ks*2 + nt], ck[nt]);
            }
        #pragma unroll
        for (int nt = 0; nt < 2; ++nt)
            #pragma unroll
            for (int r = 0; r < 4; ++r) {
                int orow = w*32 + mt*16 + hi*4 + r, ocol = nt*16 + lo;
                sq[orow * 36 + ocol] = f2b(cq[nt][r]);
                sk[orow * 36 + ocol] = f2b(ck[nt][r]);
            }
    }
    __syncthreads();   // B1 (guards k)

    // ph2: S_i = sum_j keep_ij * exp2(q'_i . k_j)
    {
        const unsigned* mp = (const unsigned*)(ws + WS_MASK) + bs * 512;
        float* gS = (float*)(ws + WS_S) + ((size_t)bs * 8 + h) * 128;
        bf16x8 aq0 = ldb8(sq + (w*32 + lo) * 36 + hi*8);
        bf16x8 aq1 = ldb8(sq + (w*32 + 16 + lo) * 36 + hi*8);
        float Sp[8];
        #pragma unroll
        for (int r2 = 0; r2 < 8; ++r2) Sp[r2] = 0.f;
        #pragma unroll 1
        for (int ntp = 0; ntp < 4; ++ntp) {
            unsigned w8[8];
            #pragma unroll
            for (int mt = 0; mt < 2; ++mt)
                #pragma unroll
                for (int r = 0; r < 4; ++r)
                    w8[mt*4 + r] = mp[(w*32 + mt*16 + hi*4 + r) * 4 + ntp] >> lo;
            #pragma unroll
            for (int sub = 0; sub < 2; ++sub) {
                int nt = ntp * 2 + sub;
                bf16x8 bk = ldb8(sk + (nt*16 + lo) * 36 + hi*8);
                f32x4 cc[2];
                cc[0] = MFMA16(aq0, bk, Z4);
                cc[1] = MFMA16(aq1, bk, Z4);
                #pragma unroll
                for (int mt = 0; mt < 2; ++mt)
                    #pragma unroll
                    for (int r = 0; r < 4; ++r) {
                        float e = EXP2F(cc[mt][r]);
                        Sp[mt*4 + r] += (w8[mt*4 + r] & (1u << (sub * 16))) ? e : 0.f;
                    }
            }
        }
        #pragma unroll
        for (int m = 1; m <= 8; m <<= 1)
            #pragma unroll
            for (int r2 = 0; r2 < 8; ++r2) Sp[r2] += __shfl_xor(Sp[r2], m);
        if (lo == 0)
            #pragma unroll
            for (int mt = 0; mt < 2; ++mt)
                #pragma unroll
                for (int r = 0; r < 4; ++r)
                    gS[w*32 + mt*16 + hi*4 + r] = Sp[mt*4 + r];
    }
}

// ================= K2: C2 + LN/C1 + FF + out (zero barriers) =================
template<int PREH0>
__global__ __launch_bounds__(256, 2) void gat_k2(
    const float* __restrict__ h0, const char* __restrict__ ws, float* __restrict__ out)
{
    const int t = threadIdx.x;
    const int bid  = blockIdx.x;
    const int slot = bid >> 3;
    const int bs   = (bid & 7) * 50 + (slot >> 3);
    const int h    = slot & 7;
    const int w = t >> 6, l = t & 63, lo = l & 15, hi = l >> 4;

    extern __shared__ char sm[];
    short* ssc = (short*)(sm + K2_SC);     // sc -> f1 (own-wave stripes)
    short* sf1 = ssc;

    const float* gvec = (const float*)(ws + WS_VEC);
    const f32x4 Z4 = {0.f, 0.f, 0.f, 0.f};
    const float Mw = gvec[512], Mb = gvec[513], Eww = gvec[514], Ewb = gvec[515], Ebb = gvec[516];
    const float* vA = gvec, *vB = gvec + 128, *vN = gvec + 256;

    // C2 = h0 @ Wav^T
    f32x4 C2[2][2];
    {
        bf16x8 wavf[8];
        const short* gWav = (const short*)(ws + WS_WAV) + h * 4096;
        #pragma unroll
        for (int i = 0; i < 8; ++i)
            wavf[i] = *(const bf16x8*)(gWav + (i * 64 + l) * 8);
        #pragma unroll
        for (int mt = 0; mt < 2; ++mt) {
            bf16x8 af[4];
            if constexpr (PREH0) {
                const short* h0w = (const short*)(ws + WS_H0) + (size_t)bs * 16384;
                #pragma unroll
                for (int ks = 0; ks < 4; ++ks)
                    af[ks] = *(const bf16x8*)(h0w + (w*32 + mt*16 + lo) * 128 + ks*32 + hi*8);
            } else {
                const float* rp = h0 + (size_t)bs * 16384 + (w*32 + mt*16 + lo) * 128;
                #pragma unroll
                for (int ks = 0; ks < 4; ++ks) {
                    float x[8]; ldg8(rp + ks*32 + hi*8, x);
                    #pragma unroll
                    for (int r = 0; r < 8; ++r) af[ks][r] = f2b(x[r]);
                }
            }
            f32x4 c2[2]; c2[0]=Z4; c2[1]=Z4;
            #pragma unroll
            for (int ks = 0; ks < 4; ++ks)
                #pragma unroll
                for (int nt = 0; nt < 2; ++nt)
                    c2[nt] = MFMA16(af[ks], wavf[ks*2 + nt], c2[nt]);
            C2[mt][0] = c2[0]; C2[mt][1] = c2[1];
        }
    }

    // AS B-frags -> regs
    bf16x8 asf[8];
    {
        const short* gAS = (const short*)(ws + WS_AS);
        #pragma unroll
        for (int i = 0; i < 8; ++i)
            asf[i] = *(const bf16x8*)(gAS + (i * 64 + l) * 8);
    }
    // biases per-lane
    float battb[2], bff1[2], bff2[2], brz[2];
    #pragma unroll
    for (int nt = 0; nt < 2; ++nt) {
        int col = nt*16 + lo;
        battb[nt] = gvec[384 + col];
        bff1[nt]  = gvec[416 + col];
        bff2[nt]  = gvec[448 + col];
        brz[nt]   = gvec[480 + col];
    }

    // LN/exp + C1 = E @ AS^T
    const float* gS = (const float*)(ws + WS_S) + ((size_t)bs * 8 + h) * 128;
    f32x4 C1[2][2];
    float c1s[2], c2s[2], Zp[2];
    #pragma unroll
    for (int mt = 0; mt < 2; ++mt) {
        float S = gS[w*32 + mt*16 + lo];
        float mu = S * Mw + Mb;
        float Et2 = S * S * Eww + 2.f * S * Ewb + Ebb;
        float rl = rsqrtf((Et2 - mu * mu) + 1e-5f) * LOG2E;
        c1s[mt] = rl * S; c2s[mt] = rl;
        Zp[mt] = 0.f;
        C1[mt][0] = Z4; C1[mt][1] = Z4;
    }
    #pragma unroll
    for (int ks = 0; ks < 4; ++ks) {
        int jb = ks * 32 + hi * 8;
        float A8[8], B8[8], N8[8];
        ldg8(vA + jb, A8); ldg8(vB + jb, B8); ldg8(vN + jb, N8);
        bf16x8 ea[2];
        #pragma unroll
        for (int mt = 0; mt < 2; ++mt)
            #pragma unroll
            for (int r = 0; r < 8; ++r) {
                float y = fmaf(c1s[mt], A8[r], fmaf(c2s[mt], B8[r], N8[r]));
                float e = EXP2F(y);
                Zp[mt] += e;
                ea[mt][r] = f2b(e);
            }
        #pragma unroll
        for (int nt = 0; nt < 2; ++nt) {
            C1[0][nt] = MFMA16(ea[0], asf[ks*2 + nt], C1[0][nt]);
            C1[1][nt] = MFMA16(ea[1], asf[ks*2 + nt], C1[1][nt]);
        }
    }
    #pragma unroll
    for (int mt = 0; mt < 2; ++mt) {
        Zp[mt] += __shfl_xor(Zp[mt], 16);
        Zp[mt] += __shfl_xor(Zp[mt], 32);
    }
    #pragma unroll
    for (int mt = 0; mt < 2; ++mt)
        #pragma unroll
        for (int r = 0; r < 4; ++r) {
            float invZ = __builtin_amdgcn_rcpf(__shfl(Zp[mt], hi*4 + r));
            #pragma unroll
            for (int nt = 0; nt < 2; ++nt) {
                int col = nt*16 + lo;
                float sc = C1[mt][nt][r] * invZ + C2[mt][nt][r] + battb[nt];
                C1[mt][nt][r] = sc;
                ssc[(w*32 + mt*16 + hi*4 + r) * 36 + col] = f2b(sc);
            }
        }
    // own-wave stripes only — no barrier.

    // ph5: f1 = leaky(sc@W1^T + b1); W1/W2 frags from global
    bf16x8 w1f[2], w2f[2];
    {
        const short* gW1 = (const short*)(ws + WS_W1);
        const short* gW2 = (const short*)(ws + WS_W2);
        #pragma unroll
        for (int nt = 0; nt < 2; ++nt) {
            w1f[nt] = *(const bf16x8*)(gW1 + (nt*64 + l) * 8);
            w2f[nt] = *(const bf16x8*)(gW2 + (nt*64 + l) * 8);
        }
    }
    #pragma unroll
    for (int mt = 0; mt < 2; ++mt) {
        bf16x8 a = ldb8(ssc + (w*32 + mt*16 + lo) * 36 + hi*8);
        #pragma unroll
        for (int nt = 0; nt < 2; ++nt) {
            f32x4 f = MFMA16(a, w1f[nt], Z4);
            #pragma unroll
            for (int r = 0; r < 4; ++r) {
                int col = nt*16 + lo;
                float x = f[r] + bff1[nt];
                sf1[(w*32 + mt*16 + hi*4 + r) * 36 + col] = f2b(fmaxf(x, 0.01f * x));
            }
        }
    }

    // ph6: out = sc + rezero*(f1@W2^T + b2)
    {
        float* outb = out + (size_t)bs * 32768 + h * 32;
        #pragma unroll
        for (int mt = 0; mt < 2; ++mt) {
            bf16x8 a = ldb8(sf1 + (w*32 + mt*16 + lo) * 36 + hi*8);
            #pragma unroll
            for (int nt = 0; nt < 2; ++nt) {
                f32x4 f = MFMA16(a, w2f[nt], Z4);
                #pragma unroll
                for (int r = 0; r < 4; ++r) {
                    int col = nt*16 + lo;
                    int i = w*32 + mt*16 + hi*4 + r;
                    outb[i * 256 + col] = C1[mt][nt][r] + brz[nt] * (f[r] + bff2[nt]);
                }
            }
        }
    }
}

extern "C" void kernel_launch(void* const* d_in, const int* in_sizes, int n_in,
                              void* d_out, int out_size, void* d_ws, size_t ws_size,
                              hipStream_t stream) {
    const float* h0    = (const float*)d_in[0];
    const float* adj   = (const float*)d_in[1];
    const float* Wl    = (const float*)d_in[2];
    const float* Wr    = (const float*)d_in[3];
    const float* Wv    = (const float*)d_in[4];
    const float* sa_w  = (const float*)d_in[5];
    const float* sa_b  = (const float*)d_in[6];
    const float* ln_w  = (const float*)d_in[7];
    const float* ln_b  = (const float*)d_in[8];
    const float* att_w = (const float*)d_in[9];
    const float* att_b = (const float*)d_in[10];
    const float* ff_w1 = (const float*)d_in[11];
    const float* ff_b1 = (const float*)d_in[12];
    const float* ff_w2 = (const float*)d_in[13];
    const float* ff_b2 = (const float*)d_in[14];
    const float* rz    = (const float*)d_in[15];
    float* outp = (float*)d_out;
    char* ws = (char*)d_ws;

    const bool big = ws_size >= (size_t)WS_NEED_BIG;
    gat_prep<<<dim3(big ? PB_BIG : PB_SMALL), dim3(256), 0, stream>>>(
        adj, Wl, Wr, Wv, sa_w, sa_b, ln_w, ln_b,
        att_w, att_b, ff_w1, ff_b1, ff_w2, ff_b2, rz, h0, ws);
    if (big) {
        gat_k1<1><<<dim3(3200), dim3(256), K1_TOTAL, stream>>>(h0, ws);
        gat_k2<1><<<dim3(3200), dim3(256), K2_TOTAL, stream>>>(h0, ws, outp);
    } else {
        gat_k1<0><<<dim3(3200), dim3(256), K1_TOTAL, stream>>>(h0, ws);
        gat_k2<0><<<dim3(3200), dim3(256), K2_TOTAL, stream>>>(h0, ws, outp);
    }
}

// Round 19
// 60.500 us; speedup vs baseline: 1.2793x; 1.2793x over previous
//
#include <hip/hip_runtime.h>
#include <hip/hip_bf16.h>

// GraphAttentionV2 (B=8,SL=50,N=128,FIN=128,H=8,FH=32) — R19 == R13 (best).
// R13: masks JIT from global in phase2 (#pragma unroll 1), LDS 37408
// (3 blocks/CU), launch_bounds(256,2) spill-free. Total 60.6us measured.
// R14-R18 structural variants (hoist, 27KB LDS, head-pair, 512-thr,
// kernel-split) all neutral/worse -> this is the accepted configuration.

typedef __attribute__((ext_vector_type(8))) short bf16x8;
typedef __attribute__((ext_vector_type(4))) short bf16x4;
typedef __attribute__((ext_vector_type(4))) float f32x4;

#define MFMA16(a, b, c) __builtin_amdgcn_mfma_f32_16x16x32_bf16(a, b, c, 0, 0, 0)
#define EXP2F(x) __builtin_amdgcn_exp2f(x)

static __device__ __forceinline__ short f2b(float f) {
    __hip_bfloat16 b = __float2bfloat16(f);
    return *reinterpret_cast<short*>(&b);
}
static __device__ __forceinline__ bf16x8 ldb8(const short* p) {  // 2x ds_read_b64
    bf16x8 r;
    *(bf16x4*)&r = *(const bf16x4*)p;
    *((bf16x4*)&r + 1) = *(const bf16x4*)(p + 4);
    return r;
}
static __device__ __forceinline__ void ldg8(const float* p, float* d) {
    float4 x0 = *(const float4*)p, x1 = *(const float4*)(p + 4);
    d[0]=x0.x; d[1]=x0.y; d[2]=x0.z; d[3]=x0.w;
    d[4]=x1.x; d[5]=x1.y; d[6]=x1.z; d[7]=x1.w;
}

#define LOG2E 1.4426950408889634f
#define QSCALE (0.0055242717280199026f * 1.4426950408889634f)

// ---- workspace byte offsets ----
#define WS_MASK 0            // u32[400][128][4] = 819200
#define WS_WL   819200       // bf16 frag-order [8][4096] = 65536
#define WS_WR   884736
#define WS_WAV  950272       // bf16 frag-order [8][4096]: Wav = att_v @ Wv_h
#define WS_AS   1015808      // frag-order bf16[4096] = 8192
#define WS_W1   1024000      // frag-order bf16[1024] = 2048
#define WS_W2   1026048
#define WS_VEC  1028096      // f32[517]: A',B',N | att_b,ff_b1,ff_b2,rz | stats(5)
#define WS_H0   1030720      // bf16[400][128][128] = 13107200 (big-ws only)
#define WS_NEED_BIG (WS_H0 + 13107200)

// ---- prep grid layout ----
#define PB_MASK   800        // blocks 0..799: (tile, half) adj bitmask
#define PB_W      816        // blocks 800..815: (h, half) weight conversion
#define PB_SMALL  817
#define PB_BIG    1217       // +400 h0-conversion blocks

// ---- main LDS byte offsets (total 37408 -> 3 blocks/CU) ----
#define L_WL   0             // 8192 frag Wl   -> late: AS frag
#define L_WR   8192          // 8192 frag Wr   -> late: W1 @+0, W2 @+2048
#define L_Q    16384         // short[128][36]=9216: q -> f1
#define L_K    25600         // short[128][36]=9216: k -> sc
#define L_S    34816         // f32[128] = 512
#define L_VEC  35328         // f32[520] = 2080
#define L_TOTAL 37408

__global__ __launch_bounds__(256) void gat_prep(
    const float* __restrict__ adj,
    const float* __restrict__ Wl, const float* __restrict__ Wr, const float* __restrict__ Wv,
    const float* __restrict__ sa_w, const float* __restrict__ sa_b,
    const float* __restrict__ ln_w, const float* __restrict__ ln_b,
    const float* __restrict__ att_w, const float* __restrict__ att_b,
    const float* __restrict__ ff_w1, const float* __restrict__ ff_b1,
    const float* __restrict__ ff_w2, const float* __restrict__ ff_b2,
    const float* __restrict__ rezero, const float* __restrict__ h0,
    char* __restrict__ ws)
{
    const int t = threadIdx.x, bid = blockIdx.x;
    if (bid < PB_MASK) {
        // adj -> bitmask: 800 blocks, (tile, half), 16 rows each
        const int tile = bid >> 1, half = bid & 1;
        const float* ab = adj + (size_t)tile * 16384;
        unsigned* mp = (unsigned*)(ws + WS_MASK) + tile * 512;
        const int w = t >> 6, l = t & 63;
        for (int rr = 0; rr < 16; ++rr) {
            int row = half * 64 + w * 16 + rr;
            float a0 = ab[row * 128 + l]      - ((row == l)      ? 1.f : 0.f);
            float a1 = ab[row * 128 + 64 + l] - ((row == 64 + l) ? 1.f : 0.f);
            unsigned long long m0 = __ballot(a0 >= 0.1f);   // bit=1: keep
            unsigned long long m1 = __ballot(a1 >= 0.1f);
            if (l == 0) {
                uint4 v; v.x = (unsigned)m0; v.y = (unsigned)(m0 >> 32);
                v.z = (unsigned)m1; v.w = (unsigned)(m1 >> 32);
                *(uint4*)(mp + row * 4) = v;
            }
        }
    } else if (bid < PB_W) {
        // weights: 16 blocks = (h, half); each thread one frag group
        const int idx = bid - PB_MASK;
        const int h = idx >> 1, half = idx & 1;
        short* wl  = (short*)(ws + WS_WL)  + h * 4096;
        short* wr  = (short*)(ws + WS_WR)  + h * 4096;
        short* wav = (short*)(ws + WS_WAV) + h * 4096;
        const float* il = Wl + h * 4096;
        const float* ir = Wr + h * 4096;
        const float* iv = Wv + h * 4096;
        const int p = half * 256 + t;     // frag group 0..511
        const int lo = p & 15, hi = (p >> 4) & 3, nt = (p >> 6) & 1, ks = p >> 7;
        const int src = (nt * 16 + lo) * 128 + ks * 32 + hi * 8;
        float x[8]; bf16x8 o;
        ldg8(il + src, x);
        #pragma unroll
        for (int e = 0; e < 8; ++e) o[e] = f2b(x[e]);
        *(bf16x8*)(wl + p * 8) = o;
        ldg8(ir + src, x);
        #pragma unroll
        for (int e = 0; e < 8; ++e) o[e] = f2b(-x[e]);   // pre-negated
        *(bf16x8*)(wr + p * 8) = o;
        // Wav[g][c] = sum_f att_v[g][f] * Wv_h[f][c]  (fp32, then bf16)
        const int g = nt * 16 + lo, c0 = ks * 32 + hi * 8;
        float acc[8];
        #pragma unroll
        for (int e = 0; e < 8; ++e) acc[e] = 0.f;
        for (int f = 0; f < 32; ++f) {
            float a = att_w[g * 160 + 128 + f];
            float v8[8]; ldg8(iv + f * 128 + c0, v8);
            #pragma unroll
            for (int e = 0; e < 8; ++e) acc[e] = fmaf(a, v8[e], acc[e]);
        }
        #pragma unroll
        for (int e = 0; e < 8; ++e) o[e] = f2b(acc[e]);
        *(bf16x8*)(wav + p * 8) = o;
    } else if (bid == PB_W) {
        __shared__ float st[5];
        short* as_ = (short*)(ws + WS_AS);
        short* w1  = (short*)(ws + WS_W1);
        short* w2  = (short*)(ws + WS_W2);
        float* vec = (float*)(ws + WS_VEC);
        #pragma unroll
        for (int pp = 0; pp < 2; ++pp) {   // att_w[:, :128] frag-order
            int p = t + pp * 256;
            int lo = p & 15, hi = (p >> 4) & 3, nt = (p >> 6) & 1, ks = p >> 7;
            float x[8]; bf16x8 o;
            ldg8(att_w + (nt * 16 + lo) * 160 + ks * 32 + hi * 8, x);
            #pragma unroll
            for (int e = 0; e < 8; ++e) o[e] = f2b(x[e]);
            *(bf16x8*)(as_ + p * 8) = o;
        }
        if (t < 128) {   // 32x32 frags: W1, W2
            int p = t, lo = p & 15, hi = (p >> 4) & 3, nt = p >> 6;
            int r = nt * 16 + lo, c = hi * 8;
            float x[8]; bf16x8 o;
            ldg8(ff_w1 + r * 32 + c, x);
            #pragma unroll
            for (int e = 0; e < 8; ++e) o[e] = f2b(x[e]);
            *(bf16x8*)(w1 + p * 8) = o;
            ldg8(ff_w2 + r * 32 + c, x);
            #pragma unroll
            for (int e = 0; e < 8; ++e) o[e] = f2b(x[e]);
            *(bf16x8*)(w2 + p * 8) = o;
        }
        if (t < 64) {   // 5 scalar stats of sa_w/sa_b
            float w0 = sa_w[t], b0 = sa_b[t], w1f = sa_w[t + 64], b1f = sa_b[t + 64];
            float sw = w0 + w1f, sb = b0 + b1f;
            float sww = w0*w0 + w1f*w1f, swb = w0*b0 + w1f*b1f, sbb = b0*b0 + b1f*b1f;
            #pragma unroll
            for (int m = 1; m <= 32; m <<= 1) {
                sw += __shfl_xor(sw, m); sb += __shfl_xor(sb, m); sww += __shfl_xor(sww, m);
                swb += __shfl_xor(swb, m); sbb += __shfl_xor(sbb, m);
            }
            if (t == 0) {
                st[0] = sw / 128.f; st[1] = sb / 128.f; st[2] = sww / 128.f;
                st[3] = swb / 128.f; st[4] = sbb / 128.f;
                vec[512] = st[0]; vec[513] = st[1]; vec[514] = st[2];
                vec[515] = st[3]; vec[516] = st[4];
            }
        }
        __syncthreads();
        if (t < 128) {
            float lw = ln_w[t];
            vec[t]       = lw * (sa_w[t] - st[0]);   // A' (pre-centered)
            vec[128 + t] = lw * (sa_b[t] - st[1]);   // B'
            vec[256 + t] = ln_b[t] * LOG2E;          // N (pre-scaled for exp2)
        } else if (t < 160) {
            int c = t - 128;
            vec[384 + c] = att_b[c];
            vec[416 + c] = ff_b1[c];
            vec[448 + c] = ff_b2[c];
            vec[480 + c] = rezero[c];
        }
    } else {
        // h0 -> bf16 (big-ws launches only)
        const int bh = bid - PB_SMALL;
        const float* hp = h0 + (size_t)bh * 16384;
        short* op = (short*)(ws + WS_H0) + (size_t)bh * 16384;
        #pragma unroll
        for (int k = 0; k < 8; ++k) {
            int idx8 = t + k * 256;
            float x[8]; bf16x8 o;
            ldg8(hp + idx8 * 8, x);
            #pragma unroll
            for (int e = 0; e < 8; ++e) o[e] = f2b(x[e]);
            *(bf16x8*)(op + idx8 * 8) = o;
        }
    }
}

template<int PREH0>
__global__ __launch_bounds__(256, 2) void gat_main(
    const float* __restrict__ h0, const char* __restrict__ ws, float* __restrict__ out)
{
    const int t = threadIdx.x;
    const int bid  = blockIdx.x;
    const int slot = bid >> 3;
    const int bs   = (bid & 7) * 50 + (slot >> 3);   // all 8 heads of a bs on one XCD
    const int h    = slot & 7;
    const int w = t >> 6, l = t & 63, lo = l & 15, hi = l >> 4;

    extern __shared__ char sm[];
    short* sWl  = (short*)(sm + L_WL);
    short* sWr  = (short*)(sm + L_WR);
    short* sq   = (short*)(sm + L_Q);
    short* sk   = (short*)(sm + L_K);
    float* sS   = (float*)(sm + L_S);
    float* svec = (float*)(sm + L_VEC);
    // overlays
    short* sAS = sWl;                       // staged after B1
    short* sW1 = sWr;
    short* sW2 = (short*)(sm + L_WR + 2048);
    short* ssc = sk;                        // sc -> k space (k dead after ph2+B2)
    short* sf1 = sq;                        // f1 -> q space (q own-stripe dead)

    const f32x4 Z4 = {0.f, 0.f, 0.f, 0.f};

    // ---- Wav B-frags: global -> regs (coalesced 16B/lane, L2/L3-hot) ----
    bf16x8 wavf[8];
    {
        const short* gWav = (const short*)(ws + WS_WAV) + h * 4096;
        #pragma unroll
        for (int i = 0; i < 8; ++i)
            wavf[i] = *(const bf16x8*)(gWav + (i * 64 + l) * 8);
    }

    // ---- B0 stage: Wl/Wr frag blobs + vec ----
    {
        const short* gWl = (const short*)(ws + WS_WL) + h * 4096;
        const short* gWr = (const short*)(ws + WS_WR) + h * 4096;
        #pragma unroll
        for (int kk = 0; kk < 2; ++kk) {
            int p = t + kk * 256;
            *(bf16x8*)(sWl + p * 8) = *(const bf16x8*)(gWl + p * 8);
            *(bf16x8*)(sWr + p * 8) = *(const bf16x8*)(gWr + p * 8);
        }
        const float* vec = (const float*)(ws + WS_VEC);
        for (int idx = t; idx < 517; idx += 256) svec[idx] = vec[idx];
    }
    __syncthreads();

    // ---- phase1: q = (h0@Wl^T)*QSCALE, k = h0@(-Wr)^T, C2 = h0@Wav^T ----
    f32x4 C2[2][2];
    #pragma unroll
    for (int mt = 0; mt < 2; ++mt) {
        bf16x8 af[4];
        if constexpr (PREH0) {
            const short* h0w = (const short*)(ws + WS_H0) + (size_t)bs * 16384;
            #pragma unroll
            for (int ks = 0; ks < 4; ++ks)
                af[ks] = *(const bf16x8*)(h0w + (w*32 + mt*16 + lo) * 128 + ks*32 + hi*8);
        } else {
            const float* rp = h0 + (size_t)bs * 16384 + (w*32 + mt*16 + lo) * 128;
            #pragma unroll
            for (int ks = 0; ks < 4; ++ks) {
                float x[8]; ldg8(rp + ks*32 + hi*8, x);
                #pragma unroll
                for (int r = 0; r < 8; ++r) af[ks][r] = f2b(x[r]);
            }
        }
        f32x4 cq[2], ck[2], c2[2];
        cq[0]=Z4; cq[1]=Z4; ck[0]=Z4; ck[1]=Z4; c2[0]=Z4; c2[1]=Z4;
        #pragma unroll
        for (int ks = 0; ks < 4; ++ks)
            #pragma unroll
            for (int nt = 0; nt < 2; ++nt) {
                int fo = ((ks*2 + nt)*64 + l) * 8;
                bf16x8 bq = *(const bf16x8*)(sWl + fo);
                bf16x8 bk = *(const bf16x8*)(sWr + fo);
                cq[nt] = MFMA16(af[ks], bq, cq[nt]);
                ck[nt] = MFMA16(af[ks], bk, ck[nt]);
                c2[nt] = MFMA16(af[ks], wavf[ks*2 + nt], c2[nt]);
            }
        #pragma unroll
        for (int nt = 0; nt < 2; ++nt) {
            C2[mt][nt] = c2[nt];
            #pragma unroll
            for (int r = 0; r < 4; ++r) {
                int orow = w*32 + mt*16 + hi*4 + r, ocol = nt*16 + lo;
                sq[orow * 36 + ocol] = f2b(cq[nt][r] * QSCALE);
                sk[orow * 36 + ocol] = f2b(ck[nt][r]);
            }
        }
    }
    __syncthreads();   // B1

    // ---- overlay stage (overlaps ph2 of other waves): AS/W1/W2 ----
    {
        const short* gAS = (const short*)(ws + WS_AS);
        #pragma unroll
        for (int kk = 0; kk < 2; ++kk) {
            int p = t + kk * 256;
            *(bf16x8*)(sAS + p * 8) = *(const bf16x8*)(gAS + p * 8);
        }
        const short* gW1 = (const short*)(ws + WS_W1);   // W1|W2 contiguous
        *(bf16x8*)(sW1 + t * 8) = *(const bf16x8*)(gW1 + t * 8);
    }
    // ---- phase2: S_i = sum_j keep_ij * exp2(q'_i . k_j); masks JIT from global ----
    {
        const unsigned* mp = (const unsigned*)(ws + WS_MASK) + bs * 512;
        bf16x8 aq0 = ldb8(sq + (w*32 + lo) * 36 + hi*8);
        bf16x8 aq1 = ldb8(sq + (w*32 + 16 + lo) * 36 + hi*8);
        float Sp[8];
        #pragma unroll
        for (int r2 = 0; r2 < 8; ++r2) Sp[r2] = 0.f;
        #pragma unroll 1
        for (int ntp = 0; ntp < 4; ++ntp) {
            unsigned w8[8];
            #pragma unroll
            for (int mt = 0; mt < 2; ++mt)
                #pragma unroll
                for (int r = 0; r < 4; ++r)
                    w8[mt*4 + r] = mp[(w*32 + mt*16 + hi*4 + r) * 4 + ntp] >> lo;
            #pragma unroll
            for (int sub = 0; sub < 2; ++sub) {
                int nt = ntp * 2 + sub;
                bf16x8 bk = ldb8(sk + (nt*16 + lo) * 36 + hi*8);
                f32x4 cc[2];
                cc[0] = MFMA16(aq0, bk, Z4);
                cc[1] = MFMA16(aq1, bk, Z4);
                #pragma unroll
                for (int mt = 0; mt < 2; ++mt)
                    #pragma unroll
                    for (int r = 0; r < 4; ++r) {
                        float e = EXP2F(cc[mt][r]);
                        Sp[mt*4 + r] += (w8[mt*4 + r] & (1u << (sub * 16))) ? e : 0.f;
                    }
            }
        }
        #pragma unroll
        for (int m = 1; m <= 8; m <<= 1)
            #pragma unroll
            for (int r2 = 0; r2 < 8; ++r2) Sp[r2] += __shfl_xor(Sp[r2], m);
        if (lo == 0)
            #pragma unroll
            for (int mt = 0; mt < 2; ++mt)
                #pragma unroll
                for (int r = 0; r < 4; ++r)
                    sS[w*32 + mt*16 + hi*4 + r] = Sp[mt*4 + r];
    }
    __syncthreads();   // B2: k dead everywhere; AS/W1/W2 visible

    // ---- phase4: E = exp2(c1*A' + c2*B' + N), C1 = E@att_s^T, sc ----
    const float Mw = svec[512], Mb = svec[513], Eww = svec[514], Ewb = svec[515], Ebb = svec[516];
    const float* vA = svec, *vB = svec + 128, *vN = svec + 256;
    f32x4 C1[2][2];
    float c1s[2], c2s[2], Zp[2];
    #pragma unroll
    for (int mt = 0; mt < 2; ++mt) {
        float S = sS[w*32 + mt*16 + lo];
        float mu = S * Mw + Mb;
        float Et2 = S * S * Eww + 2.f * S * Ewb + Ebb;
        float rl = rsqrtf((Et2 - mu * mu) + 1e-5f) * LOG2E;
        c1s[mt] = rl * S; c2s[mt] = rl;
        Zp[mt] = 0.f;
        C1[mt][0] = Z4; C1[mt][1] = Z4;
    }
    #pragma unroll
    for (int ks = 0; ks < 4; ++ks) {
        int jb = ks * 32 + hi * 8;
        float A8[8], B8[8], N8[8];
        ldg8(vA + jb, A8); ldg8(vB + jb, B8); ldg8(vN + jb, N8);
        bf16x8 ea[2];
        #pragma unroll
        for (int mt = 0; mt < 2; ++mt)
            #pragma unroll
            for (int r = 0; r < 8; ++r) {
                float y = fmaf(c1s[mt], A8[r], fmaf(c2s[mt], B8[r], N8[r]));
                float e = EXP2F(y);
                Zp[mt] += e;
                ea[mt][r] = f2b(e);
            }
        #pragma unroll
        for (int nt = 0; nt < 2; ++nt) {
            bf16x8 bb = *(const bf16x8*)(sAS + ((ks*2 + nt)*64 + l) * 8);
            C1[0][nt] = MFMA16(ea[0], bb, C1[0][nt]);
            C1[1][nt] = MFMA16(ea[1], bb, C1[1][nt]);
        }
    }
    #pragma unroll
    for (int mt = 0; mt < 2; ++mt) {
        Zp[mt] += __shfl_xor(Zp[mt], 16);
        Zp[mt] += __shfl_xor(Zp[mt], 32);
    }
    #pragma unroll
    for (int mt = 0; mt < 2; ++mt)
        #pragma unroll
        for (int r = 0; r < 4; ++r) {
            float invZ = __builtin_amdgcn_rcpf(__shfl(Zp[mt], hi*4 + r));
            #pragma unroll
            for (int nt = 0; nt < 2; ++nt) {
                int col = nt*16 + lo;
                float sc = C1[mt][nt][r] * invZ + C2[mt][nt][r] + svec[384 + col];
                C1[mt][nt][r] = sc;
                ssc[(w*32 + mt*16 + hi*4 + r) * 36 + col] = f2b(sc);
            }
        }
    // own-wave stripes only below — no barrier needed.

    // ---- phase5: f1 = leaky(sc@W1^T + b1) -> q space ----
    #pragma unroll
    for (int mt = 0; mt < 2; ++mt) {
        bf16x8 a = ldb8(ssc + (w*32 + mt*16 + lo) * 36 + hi*8);
        #pragma unroll
        for (int nt = 0; nt < 2; ++nt) {
            bf16x8 b1 = *(const bf16x8*)(sW1 + (nt*64 + l) * 8);
            f32x4 f = MFMA16(a, b1, Z4);
            #pragma unroll
            for (int r = 0; r < 4; ++r) {
                int col = nt*16 + lo;
                float x = f[r] + svec[416 + col];
                sf1[(w*32 + mt*16 + hi*4 + r) * 36 + col] = f2b(fmaxf(x, 0.01f * x));
            }
        }
    }

    // ---- phase6: out = sc + rezero*(f1@W2^T + b2) ----
    {
        float* outb = out + (size_t)bs * 32768 + h * 32;
        #pragma unroll
        for (int mt = 0; mt < 2; ++mt) {
            bf16x8 a = ldb8(sf1 + (w*32 + mt*16 + lo) * 36 + hi*8);
            #pragma unroll
            for (int nt = 0; nt < 2; ++nt) {
                bf16x8 b2 = *(const bf16x8*)(sW2 + (nt*64 + l) * 8);
                f32x4 f = MFMA16(a, b2, Z4);
                #pragma unroll
                for (int r = 0; r < 4; ++r) {
                    int col = nt*16 + lo;
                    int i = w*32 + mt*16 + hi*4 + r;
                    outb[i * 256 + col] = C1[mt][nt][r] + svec[480 + col] * (f[r] + svec[448 + col]);
                }
            }
        }
    }
}

extern "C" void kernel_launch(void* const* d_in, const int* in_sizes, int n_in,
                              void* d_out, int out_size, void* d_ws, size_t ws_size,
                              hipStream_t stream) {
    const float* h0    = (const float*)d_in[0];
    const float* adj   = (const float*)d_in[1];
    const float* Wl    = (const float*)d_in[2];
    const float* Wr    = (const float*)d_in[3];
    const float* Wv    = (const float*)d_in[4];
    const float* sa_w  = (const float*)d_in[5];
    const float* sa_b  = (const float*)d_in[6];
    const float* ln_w  = (const float*)d_in[7];
    const float* ln_b  = (const float*)d_in[8];
    const float* att_w = (const float*)d_in[9];
    const float* att_b = (const float*)d_in[10];
    const float* ff_w1 = (const float*)d_in[11];
    const float* ff_b1 = (const float*)d_in[12];
    const float* ff_w2 = (const float*)d_in[13];
    const float* ff_b2 = (const float*)d_in[14];
    const float* rz    = (const float*)d_in[15];
    float* outp = (float*)d_out;
    char* ws = (char*)d_ws;

    const bool big = ws_size >= (size_t)WS_NEED_BIG;
    gat_prep<<<dim3(big ? PB_BIG : PB_SMALL), dim3(256), 0, stream>>>(
        adj, Wl, Wr, Wv, sa_w, sa_b, ln_w, ln_b,
        att_w, att_b, ff_w1, ff_b1, ff_w2, ff_b2, rz, h0, ws);
    if (big)
        gat_main<1><<<dim3(3200), dim3(256), L_TOTAL, stream>>>(h0, ws, outp);
    else
        gat_main<0><<<dim3(3200), dim3(256), L_TOTAL, stream>>>(h0, ws, outp);
}